// Round 14
// baseline (239.879 us; speedup 1.0000x reference)
//
#include <hip/hip_runtime.h>

// ---- problem constants ----
#define BB 4
#define SS 2048
#define DD 1024
#define HH 16
#define MM (BB*SS)          // 8192
#define SLOG2E 0.1803368801111204f   // 0.125 * log2(e): folded into Q projection

typedef __attribute__((ext_vector_type(4))) float f32x4;
typedef __attribute__((ext_vector_type(16))) float f32x16;
typedef __attribute__((ext_vector_type(8))) short short8;
typedef __attribute__((ext_vector_type(4))) unsigned int u32x4;
typedef unsigned short u16;

__device__ __forceinline__ u16 f2bf(float f) {
  unsigned int u = __float_as_uint(f);
  u += 0x7FFF + ((u >> 16) & 1);   // RNE
  return (u16)(u >> 16);
}

__device__ __forceinline__ void gload_lds16(const void* g, void* l) {
  __builtin_amdgcn_global_load_lds(
      (__attribute__((address_space(1))) void*)(g),
      (__attribute__((address_space(3))) void*)(l),
      16, 0, 0);
}

__device__ __forceinline__ unsigned pk_bf16(float lo, float hi) {
  unsigned r;
  asm("v_cvt_pk_bf16_f32 %0, %1, %2" : "=v"(r) : "v"(lo), "v"(hi));
  return r;
}

__device__ __forceinline__ float ex2(float x) {
#if __has_builtin(__builtin_amdgcn_exp2f)
  return __builtin_amdgcn_exp2f(x);
#else
  return exp2f(x);
#endif
}

// swap_half(a,b) -> x = {a.lo32, b.lo32}, y = {a.hi32, b.hi32}
__device__ __forceinline__ void swap_half(unsigned a, unsigned b, unsigned& x, unsigned& y) {
#if __has_builtin(__builtin_amdgcn_permlane32_swap)
  auto r = __builtin_amdgcn_permlane32_swap(a, b, false, false);
  x = r[0]; y = r[1];
#else
  unsigned ax = (unsigned)__shfl_xor((int)a, 32, 64);
  unsigned bx = (unsigned)__shfl_xor((int)b, 32, 64);
  bool hb = (threadIdx.x & 32) != 0;
  x = hb ? bx : a;
  y = hb ? b : ax;
#endif
}

__device__ __forceinline__ float xchg_half(float v) {
  unsigned x, y;
  swap_half(__float_as_uint(v), __float_as_uint(v), x, y);
  return __uint_as_float((threadIdx.x & 32) ? x : y);
}

// ---- all 4 weight transposes in one launch: W [K][N] fp32 -> WT [N][K] bf16 ----
__global__ __launch_bounds__(256) void wtrans4_kernel(const float* __restrict__ Wq,
                                                      const float* __restrict__ Wk,
                                                      const float* __restrict__ Wv,
                                                      const float* __restrict__ Wo,
                                                      u16* __restrict__ WT) {
  const int z = blockIdx.z;
  const float* W = (z == 0) ? Wq : (z == 1) ? Wk : (z == 2) ? Wv : Wo;
  u16* dst = WT + (size_t)z * DD * DD;
  __shared__ float t[32][33];
  int n0 = blockIdx.x * 32, k0 = blockIdx.y * 32;
  int tx = threadIdx.x, ty = threadIdx.y;  // 32 x 8
  #pragma unroll
  for (int r = 0; r < 32; r += 8) t[r + ty][tx] = W[(size_t)(k0 + r + ty) * DD + n0 + tx];
  __syncthreads();
  #pragma unroll
  for (int r = 0; r < 32; r += 8) dst[(size_t)(n0 + r + ty) * DD + k0 + tx] = f2bf(t[tx][r + ty]);
}

// ---- GEMM: C[M][N] = A[M][K] * Bt[N][K]^T + bias, fp32 acc ----
// A32: A is fp32 in global, staged to LDS as fp32 (XOR-swizzled via pre-swizzled
// source per rule 21), packed to bf16 in the frag-read path.
// QKV3: fused QKV projection — blockIdx.y in [0,24): sel = y>>3 picks the input
// tensor {q,k,v}, weight panel, bias, output region; sel 0 scaled by oscale.
// sel==2 (V): epilogue LDS-transpose (reusing staging SMEM, [64][136] u16 halves)
// then COALESCED writes into per-(b,h) V^T panels — fixes R13's 4KB-strided
// u16 scatter (WRITE_SIZE 86MB, +30us). vtrans stays deleted.
template <int A32, int BF16OUT, int QKV3>
__global__ __launch_bounds__(256) void gemm_bt(const void* __restrict__ Ap0, const void* __restrict__ Ap1,
                                               const void* __restrict__ Ap2, const u16* __restrict__ Bt,
                                               const float* __restrict__ b0, const float* __restrict__ b1,
                                               const float* __restrict__ b2, void* __restrict__ Cout,
                                               float oscale, int M, int N, int K) {
  constexpr int STAGEA = A32 ? 128 * 32 * 4 : 128 * 32 * 2;
  __shared__ __align__(16) char SMEM[STAGEA + 128 * 32 * 2];   // As | Bs (24576 for A32)
  char* As = SMEM;
  u16* Bs = (u16*)(SMEM + STAGEA);
  const int tid = threadIdx.x, lane = tid & 63, wid = tid >> 6;
  const int wr = wid >> 1, wc = wid & 1;
  const int fr = lane & 15, fq = lane >> 4;
  const int mt = blockIdx.x;
  const int ntg = blockIdx.y;
  const int sel = QKV3 ? (ntg >> 3) : 0;
  const int nt = QKV3 ? (ntg & 7) : ntg;
  const void* Ap = QKV3 ? (sel == 0 ? Ap0 : sel == 1 ? Ap1 : Ap2) : Ap0;

  f32x4 acc[4][4];
  #pragma unroll
  for (int m = 0; m < 4; ++m)
    #pragma unroll
    for (int n = 0; n < 4; ++n) acc[m][n] = (f32x4)0.0f;

  const int sRow = lane >> 2;              // bf16 staging: 16 rows/KB chunk
  const int sCol = (lane & 3) * 8;
  const int srowA = lane >> 3;             // fp32 staging: 8 rows/KB chunk
  const int scolA = ((lane & 7) ^ srowA) * 4;  // pre-swizzled source col (floats)

  const float* gA32 = (const float*)Ap + (size_t)(mt * 128) * K;
  const u16*   gA16 = (const u16*)Ap + (size_t)(mt * 128) * K;
  const u16*   gB   = Bt + (QKV3 ? (size_t)sel * DD * DD : 0) + (size_t)(nt * 128) * K;

  for (int kt = 0; kt < K; kt += 32) {
    __syncthreads();
    if (A32) {
      #pragma unroll
      for (int i = 0; i < 4; ++i) {
        int ci = wid * 4 + i;
        gload_lds16(gA32 + (size_t)(ci * 8 + srowA) * K + kt + scolA, As + ci * 1024);
      }
    } else {
      #pragma unroll
      for (int r = 0; r < 2; ++r) {
        int ci = r * 4 + wid;
        gload_lds16(gA16 + (size_t)(ci * 16 + sRow) * K + kt + sCol, As + ci * 1024);
      }
    }
    #pragma unroll
    for (int r = 0; r < 2; ++r) {
      int ci = r * 4 + wid;
      gload_lds16(gB + (size_t)(ci * 16 + sRow) * K + kt + sCol, (char*)Bs + ci * 1024);
    }
    __syncthreads();

    short8 a[4], b[4];
    if (A32) {
      #pragma unroll
      for (int m = 0; m < 4; ++m) {
        int R = wr * 64 + m * 16 + fr;
        const char* base = As + R * 128;
        f32x4 lo  = *(const f32x4*)(base + (((fq * 2    ) ^ (R & 7)) << 4));
        f32x4 hi4 = *(const f32x4*)(base + (((fq * 2 + 1) ^ (R & 7)) << 4));
        u32x4 w;
        w[0] = pk_bf16(lo[0], lo[1]);   w[1] = pk_bf16(lo[2], lo[3]);
        w[2] = pk_bf16(hi4[0], hi4[1]); w[3] = pk_bf16(hi4[2], hi4[3]);
        a[m] = __builtin_bit_cast(short8, w);
      }
    } else {
      #pragma unroll
      for (int m = 0; m < 4; ++m)
        a[m] = *(const short8*)((const u16*)As + (wr * 64 + m * 16 + fr) * 32 + fq * 8);
    }
    #pragma unroll
    for (int n = 0; n < 4; ++n)
      b[n] = *(const short8*)(Bs + (wc * 64 + n * 16 + fr) * 32 + fq * 8);
    #pragma unroll
    for (int m = 0; m < 4; ++m)
      #pragma unroll
      for (int n = 0; n < 4; ++n)
        acc[m][n] = __builtin_amdgcn_mfma_f32_16x16x32_bf16(a[m], b[n], acc[m][n], 0, 0, 0);
  }

  const float* bias = QKV3 ? (sel == 0 ? b0 : sel == 1 ? b1 : b2) : b0;
  const float os = (QKV3 && sel != 0) ? 1.0f : oscale;
  u16* dst16 = (u16*)Cout + (QKV3 ? (size_t)sel * MM * DD : 0);

  const int rowBase = mt * 128 + wr * 64;
  const int colBase = nt * 128 + wc * 64;

  if (QKV3 && sel == 2) {
    // V^T epilogue via LDS transpose: two d-half passes of [64][136] u16.
    u16* T = (u16*)SMEM;
    const int sB16 = (mt >> 4) * 16;            // (s>>11)*16  (b panel base)
    const int srem = (mt * 128) & 2047;         // s offset within 2048-panel
    #pragma unroll
    for (int hh = 0; hh < 2; ++hh) {
      __syncthreads();
      if (wc == hh) {
        #pragma unroll
        for (int n = 0; n < 4; ++n) {
          int dh = n * 16 + fr;                 // 0..63 within this half
          float bi2 = bias[nt * 128 + hh * 64 + dh];
          #pragma unroll
          for (int m = 0; m < 4; ++m)
            #pragma unroll
            for (int r2 = 0; r2 < 4; ++r2) {
              int sl = wr * 64 + m * 16 + fq * 4 + r2;   // s_local 0..127
              T[dh * 136 + sl] = f2bf(acc[m][n][r2] + bi2);
            }
        }
      }
      __syncthreads();
      // coalesced write-out: 64 d x 16 chunks(16B) = 1024 chunks, 4 per thread
      #pragma unroll
      for (int i = 0; i < 4; ++i) {
        int c = i * 256 + tid;
        int dh = c >> 4;                        // 0..63
        int s8 = (c & 15) * 8;                  // s_local chunk start
        short8 val = *(const short8*)(T + dh * 136 + s8);
        size_t dstrow = ((size_t)(sB16 + nt * 2 + hh) * 64 + dh) * 2048 + srem;
        *(short8*)(dst16 + dstrow + s8) = val;
      }
    }
  } else {
    #pragma unroll
    for (int n = 0; n < 4; ++n) {
      int col = colBase + n * 16 + fr;
      float bi = bias[col];
      #pragma unroll
      for (int m = 0; m < 4; ++m) {
        #pragma unroll
        for (int r2 = 0; r2 < 4; ++r2) {
          int row = rowBase + m * 16 + fq * 4 + r2;
          float v = (acc[m][n][r2] + bi) * os;
          if (BF16OUT) dst16[(size_t)row * N + col] = f2bf(v);
          else         ((float*)Cout)[(size_t)row * N + col] = v;
        }
      }
    }
  }
}

// ---- flash attention, swapped-QK^T, 32x32x16 MFMA, static-max softmax ----
// Exact R3/R7 kernel (measured 107us, VGPR=128, no spill). 4 waves x 64 q-rows;
// grid (bh=64, qt=8); Q pre-scaled by SCALE*log2(e) so p = exp2(S^T) directly.
// DO NOT restructure: R4/R6 (launch-bound caps) spilled, R10 (kvb interleave +
// bounds(256,3)) failed correctness. This body is load-bearing.
__global__ __launch_bounds__(256, 2) void attn_kernel(const u16* __restrict__ Qb,
                                                      const u16* __restrict__ Kb,
                                                      const u16* __restrict__ Vtg,
                                                      u16* __restrict__ Ob) {
  __shared__ __align__(16) u16 Ks[2][64 * 64];   // [kv][d], swizzled
  __shared__ __align__(16) u16 Vts[2][64 * 64];  // [d][kv], swizzled
  __shared__ float sbuf[4][2][32];

  const int tid = threadIdx.x, lane = tid & 63, wid = tid >> 6;
  const int l31 = lane & 31, hi = lane >> 5;
  const int bh = blockIdx.x, qt = blockIdx.y;
  const int b = bh >> 4, h = bh & 15;
  const size_t hb = (size_t)b * SS * DD + h * 64;
  const int swz = (lane & 7) << 4;                        // read-side XOR (bytes)
  const int lslot8 = ((lane & 7) ^ (lane >> 3)) * 8;      // stage source slot (elems)
  const int srow = lane >> 3;

  // Q fragments (B operand): col q = l31, k = d = c*16 + hi*8 + j
  const int qrow0 = qt * 256 + wid * 64;
  short8 qf[2][4];
  #pragma unroll
  for (int qb = 0; qb < 2; ++qb)
    #pragma unroll
    for (int c = 0; c < 4; ++c)
      qf[qb][c] = *(const short8*)(Qb + hb + (size_t)(qrow0 + qb * 32 + l31) * DD + c * 16 + hi * 8);

  f32x16 Oa[2][2];
  #pragma unroll
  for (int qb = 0; qb < 2; ++qb)
    #pragma unroll
    for (int dblk = 0; dblk < 2; ++dblk) Oa[qb][dblk] = (f32x16)0.0f;
  float lrow[2] = {0.0f, 0.0f};

  // staging base pointers (incremental, uniform k-tile stride)
  const u16* kS = Kb + hb + (size_t)(wid * 16 + srow) * DD + lslot8;
  const u16* vS = Vtg + ((size_t)bh * 64 + wid * 16 + srow) * SS + lslot8;
  char* kD = (char*)Ks[0] + wid * 2048;
  char* vD = (char*)Vts[0] + wid * 2048;

  auto STAGE = [&](int t, int b2) {
    gload_lds16(kS + (size_t)t * 64 * DD,          kD + b2 * 8192);
    gload_lds16(kS + (size_t)t * 64 * DD + 8 * DD, kD + b2 * 8192 + 1024);
    gload_lds16(vS + t * 64,                       vD + b2 * 8192);
    gload_lds16(vS + t * 64 + 8 * SS,              vD + b2 * 8192 + 1024);
  };

  auto COMPUTE = [&](int b2) {
    const char* Kt = (const char*)Ks[b2];
    const char* Vt = (const char*)Vts[b2];
    short8 kf[2][4];
    #pragma unroll
    for (int kvb = 0; kvb < 2; ++kvb)
      #pragma unroll
      for (int c = 0; c < 4; ++c)
        kf[kvb][c] = *(const short8*)(Kt + (kvb * 32 + l31) * 128 + ((c * 32 + hi * 16) ^ swz));

    short8 PA[2][4];
    #pragma unroll
    for (int qb = 0; qb < 2; ++qb) {
      f32x16 sA = (f32x16)0.0f, sB = (f32x16)0.0f;
      __builtin_amdgcn_s_setprio(1);
      #pragma unroll
      for (int c = 0; c < 4; ++c) {
        sA = __builtin_amdgcn_mfma_f32_32x32x16_bf16(kf[0][c], qf[qb][c], sA, 0, 0, 0);
        sB = __builtin_amdgcn_mfma_f32_32x32x16_bf16(kf[1][c], qf[qb][c], sB, 0, 0, 0);
      }
      __builtin_amdgcn_s_setprio(0);

      float pA[16], pB[16];
      #pragma unroll
      for (int r = 0; r < 16; ++r) { pA[r] = ex2(sA[r]); pB[r] = ex2(sB[r]); }

      // redistribute to PV A-frag layout via cvt_pk + half-swap
      {
        unsigned w0, w1, w2, w3;
        unsigned A0 = pk_bf16(pA[0], pA[1]),  A1 = pk_bf16(pA[2], pA[3]);
        unsigned B0 = pk_bf16(pA[4], pA[5]),  B1 = pk_bf16(pA[6], pA[7]);
        swap_half(A0, B0, w0, w2); swap_half(A1, B1, w1, w3);
        u32x4 t0; t0[0] = w0; t0[1] = w1; t0[2] = w2; t0[3] = w3;
        PA[qb][0] = __builtin_bit_cast(short8, t0);
        unsigned C0 = pk_bf16(pA[8], pA[9]),   C1 = pk_bf16(pA[10], pA[11]);
        unsigned D0 = pk_bf16(pA[12], pA[13]), D1 = pk_bf16(pA[14], pA[15]);
        swap_half(C0, D0, w0, w2); swap_half(C1, D1, w1, w3);
        u32x4 t1; t1[0] = w0; t1[1] = w1; t1[2] = w2; t1[3] = w3;
        PA[qb][1] = __builtin_bit_cast(short8, t1);
        unsigned E0 = pk_bf16(pB[0], pB[1]),  E1 = pk_bf16(pB[2], pB[3]);
        unsigned F0 = pk_bf16(pB[4], pB[5]),  F1 = pk_bf16(pB[6], pB[7]);
        swap_half(E0, F0, w0, w2); swap_half(E1, F1, w1, w3);
        u32x4 t2; t2[0] = w0; t2[1] = w1; t2[2] = w2; t2[3] = w3;
        PA[qb][2] = __builtin_bit_cast(short8, t2);
        unsigned G0 = pk_bf16(pB[8], pB[9]),   G1 = pk_bf16(pB[10], pB[11]);
        unsigned H0 = pk_bf16(pB[12], pB[13]), H1 = pk_bf16(pB[14], pB[15]);
        swap_half(G0, H0, w0, w2); swap_half(G1, H1, w1, w3);
        u32x4 t3; t3[0] = w0; t3[1] = w1; t3[2] = w2; t3[3] = w3;
        PA[qb][3] = __builtin_bit_cast(short8, t3);
      }

      // depth-5 tree sum of the 32 p values, then combine lane halves
      float t8[8];
      #pragma unroll
      for (int i = 0; i < 8; ++i)
        t8[i] = (pA[2 * i] + pA[2 * i + 1]) + (pB[2 * i] + pB[2 * i + 1]);
      float s = ((t8[0] + t8[1]) + (t8[2] + t8[3])) + ((t8[4] + t8[5]) + (t8[6] + t8[7]));
      lrow[qb] += s + xchg_half(s);
    }

    // PV: A = P frags, B = V^T rows (row d = dblk*32 + l31, k = kv)
    __builtin_amdgcn_s_setprio(1);
    #pragma unroll
    for (int dblk = 0; dblk < 2; ++dblk)
      #pragma unroll
      for (int kvc = 0; kvc < 4; ++kvc) {
        short8 vf = *(const short8*)(Vt + (dblk * 32 + l31) * 128 + ((kvc * 32 + hi * 16) ^ swz));
        Oa[0][dblk] = __builtin_amdgcn_mfma_f32_32x32x16_bf16(PA[0][kvc], vf, Oa[0][dblk], 0, 0, 0);
        Oa[1][dblk] = __builtin_amdgcn_mfma_f32_32x32x16_bf16(PA[1][kvc], vf, Oa[1][dblk], 0, 0, 0);
      }
    __builtin_amdgcn_s_setprio(0);
  };

  STAGE(0, 0);
  __syncthreads();

  #pragma unroll 1
  for (int kt = 0; kt < SS / 64; kt += 2) {
    STAGE(kt + 1, 1);
    COMPUTE(0);
    __syncthreads();
    if (kt + 2 < SS / 64) STAGE(kt + 2, 0);
    COMPUTE(1);
    __syncthreads();
  }

  // epilogue: redistribute 1/l per q-row via per-wave LDS (same-wave, no barrier)
  #pragma unroll
  for (int qb = 0; qb < 2; ++qb)
    if (!hi) sbuf[wid][qb][l31] = 1.0f / lrow[qb];
  #pragma unroll
  for (int qb = 0; qb < 2; ++qb)
    #pragma unroll
    for (int r = 0; r < 16; ++r) {
      float inv = sbuf[wid][qb][(r & 3) + 8 * (r >> 2) + 4 * hi];
      int qrow = qrow0 + qb * 32 + (r & 3) + 8 * (r >> 2) + 4 * hi;
      size_t orow = (size_t)(b * SS + qrow) * DD + h * 64;
      Ob[orow + l31]      = f2bf(Oa[qb][0][r] * inv);
      Ob[orow + 32 + l31] = f2bf(Oa[qb][1][r] * inv);
    }
}

extern "C" void kernel_launch(void* const* d_in, const int* in_sizes, int n_in,
                              void* d_out, int out_size, void* d_ws, size_t ws_size,
                              hipStream_t stream) {
  const float* q  = (const float*)d_in[0];
  const float* k  = (const float*)d_in[1];
  const float* v  = (const float*)d_in[2];
  const float* Wq = (const float*)d_in[3];
  const float* bq = (const float*)d_in[4];
  const float* Wk = (const float*)d_in[5];
  const float* bk = (const float*)d_in[6];
  const float* Wv = (const float*)d_in[7];
  const float* bv = (const float*)d_in[8];
  const float* Wo = (const float*)d_in[9];
  const float* bo = (const float*)d_in[10];
  float* out = (float*)d_out;

  u16* WT   = (u16*)d_ws;                  // 4 x DD*DD bf16 (Wq,Wk,Wv,Wo transposed)
  u16* Qb   = WT + (size_t)4 * DD * DD;    // sel regions contiguous: Qb | Kb | Vtg
  u16* Kb   = Qb + (size_t)MM * DD;
  u16* Vtg  = Kb + (size_t)MM * DD;        // per-(b,h) V^T panels, written by QKV GEMM
  u16* AOut = Vtg + (size_t)MM * DD;

  wtrans4_kernel<<<dim3(32, 32, 4), dim3(32, 8), 0, stream>>>(Wq, Wk, Wv, Wo, WT);

  // Fused QKV projection (A32 staging): grid 64x24 = 1536 blocks.
  // sel==2 writes V^T panels via LDS-transpose epilogue (coalesced).
  gemm_bt<1, 1, 1><<<dim3(MM / 128, 24), 256, 0, stream>>>(
      q, k, v, WT, bq, bk, bv, Qb, SLOG2E, MM, DD, DD);

  attn_kernel<<<dim3(64, 8), 256, 0, stream>>>(Qb, Kb, Vtg, AOut);
  gemm_bt<0, 0, 0><<<dim3(MM / 128, DD / 128), 256, 0, stream>>>(
      AOut, nullptr, nullptr, WT + (size_t)3 * DD * DD, bo, nullptr, nullptr, out, 1.0f, MM, DD, DD);
}

// Round 15
// 219.680 us; speedup vs baseline: 1.0919x; 1.0919x over previous
//
#include <hip/hip_runtime.h>

// ---- problem constants ----
#define BB 4
#define SS 2048
#define DD 1024
#define HH 16
#define MM (BB*SS)          // 8192
#define SLOG2E 0.1803368801111204f   // 0.125 * log2(e): folded into Q projection

typedef __attribute__((ext_vector_type(4))) float f32x4;
typedef __attribute__((ext_vector_type(16))) float f32x16;
typedef __attribute__((ext_vector_type(8))) short short8;
typedef __attribute__((ext_vector_type(4))) unsigned int u32x4;
typedef unsigned short u16;

__device__ __forceinline__ u16 f2bf(float f) {
  unsigned int u = __float_as_uint(f);
  u += 0x7FFF + ((u >> 16) & 1);   // RNE
  return (u16)(u >> 16);
}

__device__ __forceinline__ void gload_lds16(const void* g, void* l) {
  __builtin_amdgcn_global_load_lds(
      (__attribute__((address_space(1))) void*)(g),
      (__attribute__((address_space(3))) void*)(l),
      16, 0, 0);
}

__device__ __forceinline__ unsigned pk_bf16(float lo, float hi) {
  unsigned r;
  asm("v_cvt_pk_bf16_f32 %0, %1, %2" : "=v"(r) : "v"(lo), "v"(hi));
  return r;
}

__device__ __forceinline__ float ex2(float x) {
#if __has_builtin(__builtin_amdgcn_exp2f)
  return __builtin_amdgcn_exp2f(x);
#else
  return exp2f(x);
#endif
}

// swap_half(a,b) -> x = {a.lo32, b.lo32}, y = {a.hi32, b.hi32}
__device__ __forceinline__ void swap_half(unsigned a, unsigned b, unsigned& x, unsigned& y) {
#if __has_builtin(__builtin_amdgcn_permlane32_swap)
  auto r = __builtin_amdgcn_permlane32_swap(a, b, false, false);
  x = r[0]; y = r[1];
#else
  unsigned ax = (unsigned)__shfl_xor((int)a, 32, 64);
  unsigned bx = (unsigned)__shfl_xor((int)b, 32, 64);
  bool hb = (threadIdx.x & 32) != 0;
  x = hb ? bx : a;
  y = hb ? b : ax;
#endif
}

__device__ __forceinline__ float xchg_half(float v) {
  unsigned x, y;
  swap_half(__float_as_uint(v), __float_as_uint(v), x, y);
  return __uint_as_float((threadIdx.x & 32) ? x : y);
}

// ---- all 4 weight transposes in one launch: W [K][N] fp32 -> WT [N][K] bf16 ----
__global__ __launch_bounds__(256) void wtrans4_kernel(const float* __restrict__ Wq,
                                                      const float* __restrict__ Wk,
                                                      const float* __restrict__ Wv,
                                                      const float* __restrict__ Wo,
                                                      u16* __restrict__ WT) {
  const int z = blockIdx.z;
  const float* W = (z == 0) ? Wq : (z == 1) ? Wk : (z == 2) ? Wv : Wo;
  u16* dst = WT + (size_t)z * DD * DD;
  __shared__ float t[32][33];
  int n0 = blockIdx.x * 32, k0 = blockIdx.y * 32;
  int tx = threadIdx.x, ty = threadIdx.y;  // 32 x 8
  #pragma unroll
  for (int r = 0; r < 32; r += 8) t[r + ty][tx] = W[(size_t)(k0 + r + ty) * DD + n0 + tx];
  __syncthreads();
  #pragma unroll
  for (int r = 0; r < 32; r += 8) dst[(size_t)(n0 + r + ty) * DD + k0 + tx] = f2bf(t[tx][r + ty]);
}

// ---- V [M][D] bf16 -> per-head V^T : Vtg[(bh*64 + d)*SS + s] ----
__global__ __launch_bounds__(256) void vtrans_kernel(const u16* __restrict__ Vb,
                                                     u16* __restrict__ Vtg) {
  __shared__ u16 T[64][72];
  int bh = blockIdx.x, st = blockIdx.y;
  int b = bh >> 4, h = bh & 15;
  const u16* src = Vb + ((size_t)(b * SS + st * 64)) * DD + h * 64;
  int r = threadIdx.x >> 3;        // 0..31
  int s8 = threadIdx.x & 7;
  #pragma unroll
  for (int half = 0; half < 2; ++half) {
    int row = half * 32 + r;
    short8 vv = *(const short8*)(src + (size_t)row * DD + s8 * 8);
    #pragma unroll
    for (int j = 0; j < 8; ++j) T[row][s8 * 8 + j] = (u16)vv[j];
  }
  __syncthreads();
  u16* dst = Vtg + ((size_t)bh * 64) * SS + st * 64;
  #pragma unroll
  for (int half = 0; half < 2; ++half) {
    int d = half * 32 + r;
    short8 ov;
    #pragma unroll
    for (int j = 0; j < 8; ++j) ov[j] = (short)T[s8 * 8 + j][d];
    *(short8*)(dst + (size_t)d * SS + s8 * 8) = ov;
  }
}

// ---- GEMM: C[M][N] = A[M][K] * Bt[N][K]^T + bias, fp32 acc ----
// A32: A is fp32 in global, staged to LDS as fp32 (XOR-swizzled via pre-swizzled
// source per rule 21), packed to bf16 in the frag-read path.
// QKV3: fused QKV projection — blockIdx.y in [0,24): sel = y>>3 picks the input
// tensor {q,k,v}, weight panel, bias, output buffer; sel 0 scaled by oscale.
template <int A32, int BF16OUT, int QKV3>
__global__ __launch_bounds__(256) void gemm_bt(const void* __restrict__ Ap0, const void* __restrict__ Ap1,
                                               const void* __restrict__ Ap2, const u16* __restrict__ Bt,
                                               const float* __restrict__ b0, const float* __restrict__ b1,
                                               const float* __restrict__ b2, void* __restrict__ Cout,
                                               float oscale, int M, int N, int K) {
  __shared__ __align__(16) char As[A32 ? 128 * 32 * 4 : 128 * 32 * 2];
  __shared__ __align__(16) u16 Bs[128 * 32];
  const int tid = threadIdx.x, lane = tid & 63, wid = tid >> 6;
  const int wr = wid >> 1, wc = wid & 1;
  const int fr = lane & 15, fq = lane >> 4;
  const int mt = blockIdx.x;
  const int ntg = blockIdx.y;
  const int sel = QKV3 ? (ntg >> 3) : 0;
  const int nt = QKV3 ? (ntg & 7) : ntg;
  const void* Ap = QKV3 ? (sel == 0 ? Ap0 : sel == 1 ? Ap1 : Ap2) : Ap0;

  f32x4 acc[4][4];
  #pragma unroll
  for (int m = 0; m < 4; ++m)
    #pragma unroll
    for (int n = 0; n < 4; ++n) acc[m][n] = (f32x4)0.0f;

  const int sRow = lane >> 2;              // bf16 staging: 16 rows/KB chunk
  const int sCol = (lane & 3) * 8;
  const int srowA = lane >> 3;             // fp32 staging: 8 rows/KB chunk
  const int scolA = ((lane & 7) ^ srowA) * 4;  // pre-swizzled source col (floats)

  const float* gA32 = (const float*)Ap + (size_t)(mt * 128) * K;
  const u16*   gA16 = (const u16*)Ap + (size_t)(mt * 128) * K;
  const u16*   gB   = Bt + (QKV3 ? (size_t)sel * DD * DD : 0) + (size_t)(nt * 128) * K;

  for (int kt = 0; kt < K; kt += 32) {
    __syncthreads();
    if (A32) {
      #pragma unroll
      for (int i = 0; i < 4; ++i) {
        int ci = wid * 4 + i;
        gload_lds16(gA32 + (size_t)(ci * 8 + srowA) * K + kt + scolA, As + ci * 1024);
      }
    } else {
      #pragma unroll
      for (int r = 0; r < 2; ++r) {
        int ci = r * 4 + wid;
        gload_lds16(gA16 + (size_t)(ci * 16 + sRow) * K + kt + sCol, As + ci * 1024);
      }
    }
    #pragma unroll
    for (int r = 0; r < 2; ++r) {
      int ci = r * 4 + wid;
      gload_lds16(gB + (size_t)(ci * 16 + sRow) * K + kt + sCol, (char*)Bs + ci * 1024);
    }
    __syncthreads();

    short8 a[4], b[4];
    if (A32) {
      #pragma unroll
      for (int m = 0; m < 4; ++m) {
        int R = wr * 64 + m * 16 + fr;
        const char* base = As + R * 128;
        f32x4 lo  = *(const f32x4*)(base + (((fq * 2    ) ^ (R & 7)) << 4));
        f32x4 hi4 = *(const f32x4*)(base + (((fq * 2 + 1) ^ (R & 7)) << 4));
        u32x4 w;
        w[0] = pk_bf16(lo[0], lo[1]);   w[1] = pk_bf16(lo[2], lo[3]);
        w[2] = pk_bf16(hi4[0], hi4[1]); w[3] = pk_bf16(hi4[2], hi4[3]);
        a[m] = __builtin_bit_cast(short8, w);
      }
    } else {
      #pragma unroll
      for (int m = 0; m < 4; ++m)
        a[m] = *(const short8*)((const u16*)As + (wr * 64 + m * 16 + fr) * 32 + fq * 8);
    }
    #pragma unroll
    for (int n = 0; n < 4; ++n)
      b[n] = *(const short8*)(Bs + (wc * 64 + n * 16 + fr) * 32 + fq * 8);
    #pragma unroll
    for (int m = 0; m < 4; ++m)
      #pragma unroll
      for (int n = 0; n < 4; ++n)
        acc[m][n] = __builtin_amdgcn_mfma_f32_16x16x32_bf16(a[m], b[n], acc[m][n], 0, 0, 0);
  }

  const float* bias = QKV3 ? (sel == 0 ? b0 : sel == 1 ? b1 : b2) : b0;
  const float os = (QKV3 && sel != 0) ? 1.0f : oscale;
  u16* dst16 = (u16*)Cout + (QKV3 ? (size_t)sel * MM * DD : 0);

  const int rowBase = mt * 128 + wr * 64;
  const int colBase = nt * 128 + wc * 64;
  #pragma unroll
  for (int n = 0; n < 4; ++n) {
    int col = colBase + n * 16 + fr;
    float bi = bias[col];
    #pragma unroll
    for (int m = 0; m < 4; ++m) {
      #pragma unroll
      for (int r2 = 0; r2 < 4; ++r2) {
        int row = rowBase + m * 16 + fq * 4 + r2;
        float v = (acc[m][n][r2] + bi) * os;
        if (BF16OUT) dst16[(size_t)row * N + col] = f2bf(v);
        else         ((float*)Cout)[(size_t)row * N + col] = v;
      }
    }
  }
}

// ---- flash attention, swapped-QK^T, 32x32x16 MFMA, static-max softmax ----
// Exact R3/R7 kernel (measured 107us, VGPR=128, no spill). 4 waves x 64 q-rows;
// grid (bh=64, qt=8); Q pre-scaled by SCALE*log2(e) so p = exp2(S^T) directly.
// DO NOT restructure: R4/R6 (launch-bound caps) spilled, R10 (kvb interleave +
// bounds(256,3)) failed correctness. This body is load-bearing.
__global__ __launch_bounds__(256, 2) void attn_kernel(const u16* __restrict__ Qb,
                                                      const u16* __restrict__ Kb,
                                                      const u16* __restrict__ Vtg,
                                                      u16* __restrict__ Ob) {
  __shared__ __align__(16) u16 Ks[2][64 * 64];   // [kv][d], swizzled
  __shared__ __align__(16) u16 Vts[2][64 * 64];  // [d][kv], swizzled
  __shared__ float sbuf[4][2][32];

  const int tid = threadIdx.x, lane = tid & 63, wid = tid >> 6;
  const int l31 = lane & 31, hi = lane >> 5;
  const int bh = blockIdx.x, qt = blockIdx.y;
  const int b = bh >> 4, h = bh & 15;
  const size_t hb = (size_t)b * SS * DD + h * 64;
  const int swz = (lane & 7) << 4;                        // read-side XOR (bytes)
  const int lslot8 = ((lane & 7) ^ (lane >> 3)) * 8;      // stage source slot (elems)
  const int srow = lane >> 3;

  // Q fragments (B operand): col q = l31, k = d = c*16 + hi*8 + j
  const int qrow0 = qt * 256 + wid * 64;
  short8 qf[2][4];
  #pragma unroll
  for (int qb = 0; qb < 2; ++qb)
    #pragma unroll
    for (int c = 0; c < 4; ++c)
      qf[qb][c] = *(const short8*)(Qb + hb + (size_t)(qrow0 + qb * 32 + l31) * DD + c * 16 + hi * 8);

  f32x16 Oa[2][2];
  #pragma unroll
  for (int qb = 0; qb < 2; ++qb)
    #pragma unroll
    for (int dblk = 0; dblk < 2; ++dblk) Oa[qb][dblk] = (f32x16)0.0f;
  float lrow[2] = {0.0f, 0.0f};

  // staging base pointers (incremental, uniform k-tile stride)
  const u16* kS = Kb + hb + (size_t)(wid * 16 + srow) * DD + lslot8;
  const u16* vS = Vtg + ((size_t)bh * 64 + wid * 16 + srow) * SS + lslot8;
  char* kD = (char*)Ks[0] + wid * 2048;
  char* vD = (char*)Vts[0] + wid * 2048;

  auto STAGE = [&](int t, int b2) {
    gload_lds16(kS + (size_t)t * 64 * DD,          kD + b2 * 8192);
    gload_lds16(kS + (size_t)t * 64 * DD + 8 * DD, kD + b2 * 8192 + 1024);
    gload_lds16(vS + t * 64,                       vD + b2 * 8192);
    gload_lds16(vS + t * 64 + 8 * SS,              vD + b2 * 8192 + 1024);
  };

  auto COMPUTE = [&](int b2) {
    const char* Kt = (const char*)Ks[b2];
    const char* Vt = (const char*)Vts[b2];
    short8 kf[2][4];
    #pragma unroll
    for (int kvb = 0; kvb < 2; ++kvb)
      #pragma unroll
      for (int c = 0; c < 4; ++c)
        kf[kvb][c] = *(const short8*)(Kt + (kvb * 32 + l31) * 128 + ((c * 32 + hi * 16) ^ swz));

    short8 PA[2][4];
    #pragma unroll
    for (int qb = 0; qb < 2; ++qb) {
      f32x16 sA = (f32x16)0.0f, sB = (f32x16)0.0f;
      __builtin_amdgcn_s_setprio(1);
      #pragma unroll
      for (int c = 0; c < 4; ++c) {
        sA = __builtin_amdgcn_mfma_f32_32x32x16_bf16(kf[0][c], qf[qb][c], sA, 0, 0, 0);
        sB = __builtin_amdgcn_mfma_f32_32x32x16_bf16(kf[1][c], qf[qb][c], sB, 0, 0, 0);
      }
      __builtin_amdgcn_s_setprio(0);

      float pA[16], pB[16];
      #pragma unroll
      for (int r = 0; r < 16; ++r) { pA[r] = ex2(sA[r]); pB[r] = ex2(sB[r]); }

      // redistribute to PV A-frag layout via cvt_pk + half-swap
      {
        unsigned w0, w1, w2, w3;
        unsigned A0 = pk_bf16(pA[0], pA[1]),  A1 = pk_bf16(pA[2], pA[3]);
        unsigned B0 = pk_bf16(pA[4], pA[5]),  B1 = pk_bf16(pA[6], pA[7]);
        swap_half(A0, B0, w0, w2); swap_half(A1, B1, w1, w3);
        u32x4 t0; t0[0] = w0; t0[1] = w1; t0[2] = w2; t0[3] = w3;
        PA[qb][0] = __builtin_bit_cast(short8, t0);
        unsigned C0 = pk_bf16(pA[8], pA[9]),   C1 = pk_bf16(pA[10], pA[11]);
        unsigned D0 = pk_bf16(pA[12], pA[13]), D1 = pk_bf16(pA[14], pA[15]);
        swap_half(C0, D0, w0, w2); swap_half(C1, D1, w1, w3);
        u32x4 t1; t1[0] = w0; t1[1] = w1; t1[2] = w2; t1[3] = w3;
        PA[qb][1] = __builtin_bit_cast(short8, t1);
        unsigned E0 = pk_bf16(pB[0], pB[1]),  E1 = pk_bf16(pB[2], pB[3]);
        unsigned F0 = pk_bf16(pB[4], pB[5]),  F1 = pk_bf16(pB[6], pB[7]);
        swap_half(E0, F0, w0, w2); swap_half(E1, F1, w1, w3);
        u32x4 t2; t2[0] = w0; t2[1] = w1; t2[2] = w2; t2[3] = w3;
        PA[qb][2] = __builtin_bit_cast(short8, t2);
        unsigned G0 = pk_bf16(pB[8], pB[9]),   G1 = pk_bf16(pB[10], pB[11]);
        unsigned H0 = pk_bf16(pB[12], pB[13]), H1 = pk_bf16(pB[14], pB[15]);
        swap_half(G0, H0, w0, w2); swap_half(G1, H1, w1, w3);
        u32x4 t3; t3[0] = w0; t3[1] = w1; t3[2] = w2; t3[3] = w3;
        PA[qb][3] = __builtin_bit_cast(short8, t3);
      }

      // depth-5 tree sum of the 32 p values, then combine lane halves
      float t8[8];
      #pragma unroll
      for (int i = 0; i < 8; ++i)
        t8[i] = (pA[2 * i] + pA[2 * i + 1]) + (pB[2 * i] + pB[2 * i + 1]);
      float s = ((t8[0] + t8[1]) + (t8[2] + t8[3])) + ((t8[4] + t8[5]) + (t8[6] + t8[7]));
      lrow[qb] += s + xchg_half(s);
    }

    // PV: A = P frags, B = V^T rows (row d = dblk*32 + l31, k = kv)
    __builtin_amdgcn_s_setprio(1);
    #pragma unroll
    for (int dblk = 0; dblk < 2; ++dblk)
      #pragma unroll
      for (int kvc = 0; kvc < 4; ++kvc) {
        short8 vf = *(const short8*)(Vt + (dblk * 32 + l31) * 128 + ((kvc * 32 + hi * 16) ^ swz));
        Oa[0][dblk] = __builtin_amdgcn_mfma_f32_32x32x16_bf16(PA[0][kvc], vf, Oa[0][dblk], 0, 0, 0);
        Oa[1][dblk] = __builtin_amdgcn_mfma_f32_32x32x16_bf16(PA[1][kvc], vf, Oa[1][dblk], 0, 0, 0);
      }
    __builtin_amdgcn_s_setprio(0);
  };

  STAGE(0, 0);
  __syncthreads();

  #pragma unroll 1
  for (int kt = 0; kt < SS / 64; kt += 2) {
    STAGE(kt + 1, 1);
    COMPUTE(0);
    __syncthreads();
    if (kt + 2 < SS / 64) STAGE(kt + 2, 0);
    COMPUTE(1);
    __syncthreads();
  }

  // epilogue: redistribute 1/l per q-row via per-wave LDS (same-wave, no barrier)
  #pragma unroll
  for (int qb = 0; qb < 2; ++qb)
    if (!hi) sbuf[wid][qb][l31] = 1.0f / lrow[qb];
  #pragma unroll
  for (int qb = 0; qb < 2; ++qb)
    #pragma unroll
    for (int r = 0; r < 16; ++r) {
      float inv = sbuf[wid][qb][(r & 3) + 8 * (r >> 2) + 4 * hi];
      int qrow = qrow0 + qb * 32 + (r & 3) + 8 * (r >> 2) + 4 * hi;
      size_t orow = (size_t)(b * SS + qrow) * DD + h * 64;
      Ob[orow + l31]      = f2bf(Oa[qb][0][r] * inv);
      Ob[orow + 32 + l31] = f2bf(Oa[qb][1][r] * inv);
    }
}

extern "C" void kernel_launch(void* const* d_in, const int* in_sizes, int n_in,
                              void* d_out, int out_size, void* d_ws, size_t ws_size,
                              hipStream_t stream) {
  const float* q  = (const float*)d_in[0];
  const float* k  = (const float*)d_in[1];
  const float* v  = (const float*)d_in[2];
  const float* Wq = (const float*)d_in[3];
  const float* bq = (const float*)d_in[4];
  const float* Wk = (const float*)d_in[5];
  const float* bk = (const float*)d_in[6];
  const float* Wv = (const float*)d_in[7];
  const float* bv = (const float*)d_in[8];
  const float* Wo = (const float*)d_in[9];
  const float* bo = (const float*)d_in[10];
  float* out = (float*)d_out;

  u16* WT   = (u16*)d_ws;                  // 4 x DD*DD bf16 (Wq,Wk,Wv,Wo transposed)
  u16* Qb   = WT + (size_t)4 * DD * DD;    // Qb,Kb,Vb contiguous (fused epilogue)
  u16* Kb   = Qb + (size_t)MM * DD;
  u16* Vb   = Kb + (size_t)MM * DD;
  u16* Vtg  = Vb + (size_t)MM * DD;        // per-(b,h) V^T panels [bh*64+d][SS]
  u16* AOut = Vb;                          // V rows dead after vtrans

  wtrans4_kernel<<<dim3(32, 32, 4), dim3(32, 8), 0, stream>>>(Wq, Wk, Wv, Wo, WT);

  // Fused QKV projection (A32 staging): grid 64x24 = 1536 blocks.
  gemm_bt<1, 1, 1><<<dim3(MM / 128, 24), 256, 0, stream>>>(
      q, k, v, WT, bq, bk, bv, Qb, SLOG2E, MM, DD, DD);

  vtrans_kernel<<<dim3(64, 32), 256, 0, stream>>>(Vb, Vtg);
  attn_kernel<<<dim3(64, 8), 256, 0, stream>>>(Qb, Kb, Vtg, AOut);
  gemm_bt<0, 0, 0><<<dim3(MM / 128, DD / 128), 256, 0, stream>>>(
      AOut, nullptr, nullptr, WT + (size_t)3 * DD * DD, bo, nullptr, nullptr, out, 1.0f, MM, DD, DD);
}

// Round 16
// 197.040 us; speedup vs baseline: 1.2174x; 1.1149x over previous
//
#include <hip/hip_runtime.h>

// ---- problem constants ----
#define BB 4
#define SS 2048
#define DD 1024
#define HH 16
#define MM (BB*SS)          // 8192
#define SLOG2E 0.1803368801111204f   // 0.125 * log2(e): folded into Q projection

typedef __attribute__((ext_vector_type(4))) float f32x4;
typedef __attribute__((ext_vector_type(16))) float f32x16;
typedef __attribute__((ext_vector_type(8))) short short8;
typedef __attribute__((ext_vector_type(4))) unsigned int u32x4;
typedef unsigned short u16;

__device__ __forceinline__ u16 f2bf(float f) {
  unsigned int u = __float_as_uint(f);
  u += 0x7FFF + ((u >> 16) & 1);   // RNE
  return (u16)(u >> 16);
}

__device__ __forceinline__ void gload_lds16(const void* g, void* l) {
  __builtin_amdgcn_global_load_lds(
      (__attribute__((address_space(1))) void*)(g),
      (__attribute__((address_space(3))) void*)(l),
      16, 0, 0);
}

__device__ __forceinline__ unsigned pk_bf16(float lo, float hi) {
  unsigned r;
  asm("v_cvt_pk_bf16_f32 %0, %1, %2" : "=v"(r) : "v"(lo), "v"(hi));
  return r;
}

__device__ __forceinline__ float ex2(float x) {
#if __has_builtin(__builtin_amdgcn_exp2f)
  return __builtin_amdgcn_exp2f(x);
#else
  return exp2f(x);
#endif
}

// swap_half(a,b) -> x = {a.lo32, b.lo32}, y = {a.hi32, b.hi32}
__device__ __forceinline__ void swap_half(unsigned a, unsigned b, unsigned& x, unsigned& y) {
#if __has_builtin(__builtin_amdgcn_permlane32_swap)
  auto r = __builtin_amdgcn_permlane32_swap(a, b, false, false);
  x = r[0]; y = r[1];
#else
  unsigned ax = (unsigned)__shfl_xor((int)a, 32, 64);
  unsigned bx = (unsigned)__shfl_xor((int)b, 32, 64);
  bool hb = (threadIdx.x & 32) != 0;
  x = hb ? bx : a;
  y = hb ? b : ax;
#endif
}

__device__ __forceinline__ float xchg_half(float v) {
  unsigned x, y;
  swap_half(__float_as_uint(v), __float_as_uint(v), x, y);
  return __uint_as_float((threadIdx.x & 32) ? x : y);
}

// ---- all 4 weight transposes in one launch: W [K][N] fp32 -> WT [N][K] bf16 ----
__global__ __launch_bounds__(256) void wtrans4_kernel(const float* __restrict__ Wq,
                                                      const float* __restrict__ Wk,
                                                      const float* __restrict__ Wv,
                                                      const float* __restrict__ Wo,
                                                      u16* __restrict__ WT) {
  const int z = blockIdx.z;
  const float* W = (z == 0) ? Wq : (z == 1) ? Wk : (z == 2) ? Wv : Wo;
  u16* dst = WT + (size_t)z * DD * DD;
  __shared__ float t[32][33];
  int n0 = blockIdx.x * 32, k0 = blockIdx.y * 32;
  int tx = threadIdx.x, ty = threadIdx.y;  // 32 x 8
  #pragma unroll
  for (int r = 0; r < 32; r += 8) t[r + ty][tx] = W[(size_t)(k0 + r + ty) * DD + n0 + tx];
  __syncthreads();
  #pragma unroll
  for (int r = 0; r < 32; r += 8) dst[(size_t)(n0 + r + ty) * DD + k0 + tx] = f2bf(t[tx][r + ty]);
}

// ---- V [M][D] bf16 -> per-head V^T : Vtg[(bh*64 + d)*SS + s] ----
__global__ __launch_bounds__(256) void vtrans_kernel(const u16* __restrict__ Vb,
                                                     u16* __restrict__ Vtg) {
  __shared__ u16 T[64][72];
  int bh = blockIdx.x, st = blockIdx.y;
  int b = bh >> 4, h = bh & 15;
  const u16* src = Vb + ((size_t)(b * SS + st * 64)) * DD + h * 64;
  int r = threadIdx.x >> 3;        // 0..31
  int s8 = threadIdx.x & 7;
  #pragma unroll
  for (int half = 0; half < 2; ++half) {
    int row = half * 32 + r;
    short8 vv = *(const short8*)(src + (size_t)row * DD + s8 * 8);
    #pragma unroll
    for (int j = 0; j < 8; ++j) T[row][s8 * 8 + j] = (u16)vv[j];
  }
  __syncthreads();
  u16* dst = Vtg + ((size_t)bh * 64) * SS + st * 64;
  #pragma unroll
  for (int half = 0; half < 2; ++half) {
    int d = half * 32 + r;
    short8 ov;
    #pragma unroll
    for (int j = 0; j < 8; ++j) ov[j] = (short)T[s8 * 8 + j][d];
    *(short8*)(dst + (size_t)d * SS + s8 * 8) = ov;
  }
}

// ---- GEMM: C[M][N] = A[M][K] * Bt[N][K]^T + bias, fp32 acc ----
// A32: A is fp32 in global, staged to LDS as fp32 (XOR-swizzled via pre-swizzled
// source per rule 21), packed to bf16 in the frag-read path.
// QKV3: fused QKV projection — blockIdx.y in [0,24): sel = y>>3 picks the input
// tensor {q,k,v}, weight panel, bias, output buffer; sel 0 scaled by oscale.
template <int A32, int BF16OUT, int QKV3>
__global__ __launch_bounds__(256) void gemm_bt(const void* __restrict__ Ap0, const void* __restrict__ Ap1,
                                               const void* __restrict__ Ap2, const u16* __restrict__ Bt,
                                               const float* __restrict__ b0, const float* __restrict__ b1,
                                               const float* __restrict__ b2, void* __restrict__ Cout,
                                               float oscale, int M, int N, int K) {
  __shared__ __align__(16) char As[A32 ? 128 * 32 * 4 : 128 * 32 * 2];
  __shared__ __align__(16) u16 Bs[128 * 32];
  const int tid = threadIdx.x, lane = tid & 63, wid = tid >> 6;
  const int wr = wid >> 1, wc = wid & 1;
  const int fr = lane & 15, fq = lane >> 4;
  const int mt = blockIdx.x;
  const int ntg = blockIdx.y;
  const int sel = QKV3 ? (ntg >> 3) : 0;
  const int nt = QKV3 ? (ntg & 7) : ntg;
  const void* Ap = QKV3 ? (sel == 0 ? Ap0 : sel == 1 ? Ap1 : Ap2) : Ap0;

  f32x4 acc[4][4];
  #pragma unroll
  for (int m = 0; m < 4; ++m)
    #pragma unroll
    for (int n = 0; n < 4; ++n) acc[m][n] = (f32x4)0.0f;

  const int sRow = lane >> 2;              // bf16 staging: 16 rows/KB chunk
  const int sCol = (lane & 3) * 8;
  const int srowA = lane >> 3;             // fp32 staging: 8 rows/KB chunk
  const int scolA = ((lane & 7) ^ srowA) * 4;  // pre-swizzled source col (floats)

  const float* gA32 = (const float*)Ap + (size_t)(mt * 128) * K;
  const u16*   gA16 = (const u16*)Ap + (size_t)(mt * 128) * K;
  const u16*   gB   = Bt + (QKV3 ? (size_t)sel * DD * DD : 0) + (size_t)(nt * 128) * K;

  for (int kt = 0; kt < K; kt += 32) {
    __syncthreads();
    if (A32) {
      #pragma unroll
      for (int i = 0; i < 4; ++i) {
        int ci = wid * 4 + i;
        gload_lds16(gA32 + (size_t)(ci * 8 + srowA) * K + kt + scolA, As + ci * 1024);
      }
    } else {
      #pragma unroll
      for (int r = 0; r < 2; ++r) {
        int ci = r * 4 + wid;
        gload_lds16(gA16 + (size_t)(ci * 16 + sRow) * K + kt + sCol, As + ci * 1024);
      }
    }
    #pragma unroll
    for (int r = 0; r < 2; ++r) {
      int ci = r * 4 + wid;
      gload_lds16(gB + (size_t)(ci * 16 + sRow) * K + kt + sCol, (char*)Bs + ci * 1024);
    }
    __syncthreads();

    short8 a[4], b[4];
    if (A32) {
      #pragma unroll
      for (int m = 0; m < 4; ++m) {
        int R = wr * 64 + m * 16 + fr;
        const char* base = As + R * 128;
        f32x4 lo  = *(const f32x4*)(base + (((fq * 2    ) ^ (R & 7)) << 4));
        f32x4 hi4 = *(const f32x4*)(base + (((fq * 2 + 1) ^ (R & 7)) << 4));
        u32x4 w;
        w[0] = pk_bf16(lo[0], lo[1]);   w[1] = pk_bf16(lo[2], lo[3]);
        w[2] = pk_bf16(hi4[0], hi4[1]); w[3] = pk_bf16(hi4[2], hi4[3]);
        a[m] = __builtin_bit_cast(short8, w);
      }
    } else {
      #pragma unroll
      for (int m = 0; m < 4; ++m)
        a[m] = *(const short8*)((const u16*)As + (wr * 64 + m * 16 + fr) * 32 + fq * 8);
    }
    #pragma unroll
    for (int n = 0; n < 4; ++n)
      b[n] = *(const short8*)(Bs + (wc * 64 + n * 16 + fr) * 32 + fq * 8);
    #pragma unroll
    for (int m = 0; m < 4; ++m)
      #pragma unroll
      for (int n = 0; n < 4; ++n)
        acc[m][n] = __builtin_amdgcn_mfma_f32_16x16x32_bf16(a[m], b[n], acc[m][n], 0, 0, 0);
  }

  const float* bias = QKV3 ? (sel == 0 ? b0 : sel == 1 ? b1 : b2) : b0;
  const float os = (QKV3 && sel != 0) ? 1.0f : oscale;
  u16* dst16 = (u16*)Cout + (QKV3 ? (size_t)sel * MM * DD : 0);

  const int rowBase = mt * 128 + wr * 64;
  const int colBase = nt * 128 + wc * 64;
  #pragma unroll
  for (int n = 0; n < 4; ++n) {
    int col = colBase + n * 16 + fr;
    float bi = bias[col];
    #pragma unroll
    for (int m = 0; m < 4; ++m) {
      #pragma unroll
      for (int r2 = 0; r2 < 4; ++r2) {
        int row = rowBase + m * 16 + fq * 4 + r2;
        float v = (acc[m][n][r2] + bi) * os;
        if (BF16OUT) dst16[(size_t)row * N + col] = f2bf(v);
        else         ((float*)Cout)[(size_t)row * N + col] = v;
      }
    }
  }
}

// ---- flash attention, swapped-QK^T, 32x32x16 MFMA, static-max softmax ----
// R3/R7 structure (4 waves x 64 q-rows, grid (64,8), __launch_bounds__(256,2)).
// R16 change (ISOLATED): COMPUTE interleaved per-kvb (QK MFMA -> exp2 -> pack one
// 32-kv half at a time) to halve peak s/p co-liveness. Algebra verified identical
// to R3 (PA[qb][kvb*2+j] == R3's pA->PA[0..1], pB->PA[2..3]; ls-sum == s-tree).
// Launch bounds deliberately UNCHANGED: isolates R10's failure (interleave vs
// the (256,3) register cap). If this passes, (256,3) is the next step.
__global__ __launch_bounds__(256, 2) void attn_kernel(const u16* __restrict__ Qb,
                                                      const u16* __restrict__ Kb,
                                                      const u16* __restrict__ Vtg,
                                                      u16* __restrict__ Ob) {
  __shared__ __align__(16) u16 Ks[2][64 * 64];   // [kv][d], swizzled
  __shared__ __align__(16) u16 Vts[2][64 * 64];  // [d][kv], swizzled
  __shared__ float sbuf[4][2][32];

  const int tid = threadIdx.x, lane = tid & 63, wid = tid >> 6;
  const int l31 = lane & 31, hi = lane >> 5;
  const int bh = blockIdx.x, qt = blockIdx.y;
  const int b = bh >> 4, h = bh & 15;
  const size_t hb = (size_t)b * SS * DD + h * 64;
  const int swz = (lane & 7) << 4;                        // read-side XOR (bytes)
  const int lslot8 = ((lane & 7) ^ (lane >> 3)) * 8;      // stage source slot (elems)
  const int srow = lane >> 3;

  // Q fragments (B operand): col q = l31, k = d = c*16 + hi*8 + j
  const int qrow0 = qt * 256 + wid * 64;
  short8 qf[2][4];
  #pragma unroll
  for (int qb = 0; qb < 2; ++qb)
    #pragma unroll
    for (int c = 0; c < 4; ++c)
      qf[qb][c] = *(const short8*)(Qb + hb + (size_t)(qrow0 + qb * 32 + l31) * DD + c * 16 + hi * 8);

  f32x16 Oa[2][2];
  #pragma unroll
  for (int qb = 0; qb < 2; ++qb)
    #pragma unroll
    for (int dblk = 0; dblk < 2; ++dblk) Oa[qb][dblk] = (f32x16)0.0f;
  float lrow[2] = {0.0f, 0.0f};

  // staging base pointers (incremental, uniform k-tile stride)
  const u16* kS = Kb + hb + (size_t)(wid * 16 + srow) * DD + lslot8;
  const u16* vS = Vtg + ((size_t)bh * 64 + wid * 16 + srow) * SS + lslot8;
  char* kD = (char*)Ks[0] + wid * 2048;
  char* vD = (char*)Vts[0] + wid * 2048;

  auto STAGE = [&](int t, int b2) {
    gload_lds16(kS + (size_t)t * 64 * DD,          kD + b2 * 8192);
    gload_lds16(kS + (size_t)t * 64 * DD + 8 * DD, kD + b2 * 8192 + 1024);
    gload_lds16(vS + t * 64,                       vD + b2 * 8192);
    gload_lds16(vS + t * 64 + 8 * SS,              vD + b2 * 8192 + 1024);
  };

  auto COMPUTE = [&](int b2) {
    const char* Kt = (const char*)Ks[b2];
    const char* Vt = (const char*)Vts[b2];
    short8 PA[2][4];
    float ls[2] = {0.0f, 0.0f};

    // interleaved per-kvb: QK MFMA -> exp2 -> pack, one 32-kv half at a time
    #pragma unroll
    for (int kvb = 0; kvb < 2; ++kvb) {
      short8 kf[4];
      #pragma unroll
      for (int c = 0; c < 4; ++c)
        kf[c] = *(const short8*)(Kt + (kvb * 32 + l31) * 128 + ((c * 32 + hi * 16) ^ swz));
      #pragma unroll
      for (int qb = 0; qb < 2; ++qb) {
        f32x16 s = (f32x16)0.0f;
        __builtin_amdgcn_s_setprio(1);
        #pragma unroll
        for (int c = 0; c < 4; ++c)
          s = __builtin_amdgcn_mfma_f32_32x32x16_bf16(kf[c], qf[qb][c], s, 0, 0, 0);
        __builtin_amdgcn_s_setprio(0);
        // s[r] = S^T[kv = kvb*32 + (r&3)+8*(r>>2)+4*hi][q = qrow0 + qb*32 + l31]

        float p[16];
        #pragma unroll
        for (int r = 0; r < 16; ++r) p[r] = ex2(s[r]);

        float t8[8];
        #pragma unroll
        for (int i = 0; i < 8; ++i) t8[i] = p[2 * i] + p[2 * i + 1];
        ls[qb] += ((t8[0] + t8[1]) + (t8[2] + t8[3])) + ((t8[4] + t8[5]) + (t8[6] + t8[7]));

        // redistribute to PV A-frag layout via cvt_pk + half-swap
        unsigned w0, w1, w2, w3;
        unsigned A0 = pk_bf16(p[0], p[1]),   A1 = pk_bf16(p[2], p[3]);
        unsigned B0 = pk_bf16(p[4], p[5]),   B1 = pk_bf16(p[6], p[7]);
        swap_half(A0, B0, w0, w2); swap_half(A1, B1, w1, w3);
        u32x4 t0; t0[0] = w0; t0[1] = w1; t0[2] = w2; t0[3] = w3;
        PA[qb][kvb * 2] = __builtin_bit_cast(short8, t0);
        unsigned C0 = pk_bf16(p[8], p[9]),   C1 = pk_bf16(p[10], p[11]);
        unsigned D0 = pk_bf16(p[12], p[13]), D1 = pk_bf16(p[14], p[15]);
        swap_half(C0, D0, w0, w2); swap_half(C1, D1, w1, w3);
        u32x4 t1; t1[0] = w0; t1[1] = w1; t1[2] = w2; t1[3] = w3;
        PA[qb][kvb * 2 + 1] = __builtin_bit_cast(short8, t1);
      }
    }
    #pragma unroll
    for (int qb = 0; qb < 2; ++qb)
      lrow[qb] += ls[qb] + xchg_half(ls[qb]);

    // PV: A = P frags, B = V^T rows (row d = dblk*32 + l31, k = kv)
    __builtin_amdgcn_s_setprio(1);
    #pragma unroll
    for (int dblk = 0; dblk < 2; ++dblk)
      #pragma unroll
      for (int kvc = 0; kvc < 4; ++kvc) {
        short8 vf = *(const short8*)(Vt + (dblk * 32 + l31) * 128 + ((kvc * 32 + hi * 16) ^ swz));
        Oa[0][dblk] = __builtin_amdgcn_mfma_f32_32x32x16_bf16(PA[0][kvc], vf, Oa[0][dblk], 0, 0, 0);
        Oa[1][dblk] = __builtin_amdgcn_mfma_f32_32x32x16_bf16(PA[1][kvc], vf, Oa[1][dblk], 0, 0, 0);
      }
    __builtin_amdgcn_s_setprio(0);
  };

  STAGE(0, 0);
  __syncthreads();

  #pragma unroll 1
  for (int kt = 0; kt < SS / 64; kt += 2) {
    STAGE(kt + 1, 1);
    COMPUTE(0);
    __syncthreads();
    if (kt + 2 < SS / 64) STAGE(kt + 2, 0);
    COMPUTE(1);
    __syncthreads();
  }

  // epilogue: redistribute 1/l per q-row via per-wave LDS (same-wave, no barrier)
  #pragma unroll
  for (int qb = 0; qb < 2; ++qb)
    if (!hi) sbuf[wid][qb][l31] = 1.0f / lrow[qb];
  #pragma unroll
  for (int qb = 0; qb < 2; ++qb)
    #pragma unroll
    for (int r = 0; r < 16; ++r) {
      float inv = sbuf[wid][qb][(r & 3) + 8 * (r >> 2) + 4 * hi];
      int qrow = qrow0 + qb * 32 + (r & 3) + 8 * (r >> 2) + 4 * hi;
      size_t orow = (size_t)(b * SS + qrow) * DD + h * 64;
      Ob[orow + l31]      = f2bf(Oa[qb][0][r] * inv);
      Ob[orow + 32 + l31] = f2bf(Oa[qb][1][r] * inv);
    }
}

extern "C" void kernel_launch(void* const* d_in, const int* in_sizes, int n_in,
                              void* d_out, int out_size, void* d_ws, size_t ws_size,
                              hipStream_t stream) {
  const float* q  = (const float*)d_in[0];
  const float* k  = (const float*)d_in[1];
  const float* v  = (const float*)d_in[2];
  const float* Wq = (const float*)d_in[3];
  const float* bq = (const float*)d_in[4];
  const float* Wk = (const float*)d_in[5];
  const float* bk = (const float*)d_in[6];
  const float* Wv = (const float*)d_in[7];
  const float* bv = (const float*)d_in[8];
  const float* Wo = (const float*)d_in[9];
  const float* bo = (const float*)d_in[10];
  float* out = (float*)d_out;

  u16* WT   = (u16*)d_ws;                  // 4 x DD*DD bf16 (Wq,Wk,Wv,Wo transposed)
  u16* Qb   = WT + (size_t)4 * DD * DD;    // Qb,Kb,Vb contiguous (fused epilogue)
  u16* Kb   = Qb + (size_t)MM * DD;
  u16* Vb   = Kb + (size_t)MM * DD;
  u16* Vtg  = Vb + (size_t)MM * DD;        // per-(b,h) V^T panels [bh*64+d][SS]
  u16* AOut = Vb;                          // V rows dead after vtrans

  wtrans4_kernel<<<dim3(32, 32, 4), dim3(32, 8), 0, stream>>>(Wq, Wk, Wv, Wo, WT);

  // Fused QKV projection (A32 staging): grid 64x24 = 1536 blocks.
  gemm_bt<1, 1, 1><<<dim3(MM / 128, 24), 256, 0, stream>>>(
      q, k, v, WT, bq, bk, bv, Qb, SLOG2E, MM, DD, DD);

  vtrans_kernel<<<dim3(64, 32), 256, 0, stream>>>(Vb, Vtg);
  attn_kernel<<<dim3(64, 8), 256, 0, stream>>>(Qb, Kb, Vtg, AOut);
  gemm_bt<0, 0, 0><<<dim3(MM / 128, DD / 128), 256, 0, stream>>>(
      AOut, nullptr, nullptr, WT + (size_t)3 * DD * DD, bo, nullptr, nullptr, out, 1.0f, MM, DD, DD);
}